// Round 3
// baseline (1492.178 us; speedup 1.0000x reference)
//
#include <hip/hip_runtime.h>
#include <math.h>

#define B_   64
#define N_   196
#define VD_  512
#define ED_  512
#define HD_  512
#define V_   10000
#define T_   20
#define G4_  2048   // 4*HD
#define NBLK_LSTM 256

typedef __attribute__((ext_vector_type(8))) short bf16x8;
typedef __attribute__((ext_vector_type(4))) float f32x4;

static __device__ __forceinline__ float sigmoidf_(float x) {
  return 1.f / (1.f + __expf(-x));
}

static __device__ __forceinline__ unsigned short f2bf_(float x) {
  unsigned u = __float_as_uint(x);
  unsigned r = (u + 0x7FFFu + ((u >> 16) & 1u)) >> 16;   // RNE
  return (unsigned short)r;
}

// ---------------------------------------------------------------------------
// k_prep: all fp32->bf16 weight casts + embedding gather-cast, one launch.
//   seg0 [0,5000):   W_out   [10000][512] -> wout_bf
//   seg1 [5000,6024): W_ih[:,512:1024]    -> wihe_bf [2048][512]
//   seg2 [6024,6664): embed[captions[b,t]] -> emb_bf [t*64+b][512]
// ---------------------------------------------------------------------------
__global__ void k_prep(const float* __restrict__ W_out,
                       const float* __restrict__ W_ih,
                       const float* __restrict__ embed,
                       const int* __restrict__ caps,
                       unsigned short* __restrict__ wout_bf,
                       unsigned short* __restrict__ wihe_bf,
                       unsigned short* __restrict__ emb_bf) {
  int bx = blockIdx.x, tid = threadIdx.x;
  float4 v; unsigned short* dst; int i;
  if (bx < 5000) {
    i = bx * 256 + tid;                       // float4 idx into W_out (1.28M)
    v = ((const float4*)W_out)[i];
    dst = wout_bf;
  } else if (bx < 6024) {
    i = (bx - 5000) * 256 + tid;              // 0..262143
    int j = i >> 7, kk = (i & 127) << 2;      // row j of 2048, col kk of 512
    v = *(const float4*)(W_ih + (size_t)j * (VD_ + ED_) + VD_ + kk);
    dst = wihe_bf;
  } else {
    i = (bx - 6024) * 256 + tid;              // 0..163839
    int row = i >> 7;                          // t*64+b
    int b = row & 63, t = row >> 6;
    v = *(const float4*)(embed + (size_t)caps[b * T_ + t] * ED_ + ((i & 127) << 2));
    dst = emb_bf;
  }
  ushort4 o;
  o.x = f2bf_(v.x); o.y = f2bf_(v.y); o.z = f2bf_(v.z); o.w = f2bf_(v.w);
  ((ushort4*)dst)[i] = o;
}

// ---------------------------------------------------------------------------
// k_attn1: attention logits svg[b][n] = feat[b,n,:] . W_av  (att_h/b cancel
// in softmax over n). grid (64 b, 4 n-chunks of 49); wave handles one n,
// lanes cover 512 dims (8 each), shuffle-reduce.
// ---------------------------------------------------------------------------
__global__ void k_attn1(const float* __restrict__ feat,
                        const float* __restrict__ W_av,
                        float* __restrict__ svg) {
  int b = blockIdx.x, q = blockIdx.y;
  int tid = threadIdx.x, lane = tid & 63, w = tid >> 6;
  const float* fb = feat + (size_t)b * (N_ * VD_);
  float4 wv0 = *(const float4*)(W_av + lane * 8);
  float4 wv1 = *(const float4*)(W_av + lane * 8 + 4);
  int nbase = q * 49;
  for (int n = nbase + w; n < nbase + 49; n += 4) {
    const float* fp = fb + n * VD_ + lane * 8;
    float4 f0 = *(const float4*)fp;
    float4 f1 = *(const float4*)(fp + 4);
    float p = f0.x * wv0.x + f0.y * wv0.y + f0.z * wv0.z + f0.w * wv0.w
            + f1.x * wv1.x + f1.y * wv1.y + f1.z * wv1.z + f1.w * wv1.w;
#pragma unroll
    for (int off = 32; off > 0; off >>= 1) p += __shfl_down(p, off, 64);
    if (lane == 0) svg[b * N_ + n] = p;
  }
}

// ---------------------------------------------------------------------------
// k_attn2: softmax(svg[b]) -> attention weights; ctx[b,d] = sum_n a[n]*f and
// fmean[b,d] = mean_n f for d in the block's 128-dim chunk.
// grid (64 b, 4 d-chunks); thread = (d = q*128 + tid&127, n-half = tid>>7).
// Features read exactly once across the grid.
// ---------------------------------------------------------------------------
__global__ void k_attn2(const float* __restrict__ feat,
                        const float* __restrict__ svg,
                        float* __restrict__ fmean,
                        float* __restrict__ ctx) {
  __shared__ float sa[200];
  __shared__ float red[8];
  __shared__ float pc[2][128];
  __shared__ float pf[2][128];
  int b = blockIdx.x, q = blockIdx.y;
  int tid = threadIdx.x, lane = tid & 63, w = tid >> 6;
  const float* fb = feat + (size_t)b * (N_ * VD_);

  float v = (tid < N_) ? svg[b * N_ + tid] : -1e30f;
  float m = v;
#pragma unroll
  for (int off = 32; off > 0; off >>= 1) m = fmaxf(m, __shfl_down(m, off, 64));
  if (lane == 0) red[w] = m;
  __syncthreads();
  m = fmaxf(fmaxf(red[0], red[1]), fmaxf(red[2], red[3]));

  float e = (tid < N_) ? __expf(v - m) : 0.f;
  float s = e;
#pragma unroll
  for (int off = 32; off > 0; off >>= 1) s += __shfl_down(s, off, 64);
  if (lane == 0) red[4 + w] = s;
  __syncthreads();
  float inv = 1.f / (red[4] + red[5] + red[6] + red[7]);
  if (tid < N_) sa[tid] = e * inv;
  __syncthreads();

  int d = q * 128 + (tid & 127);
  int nh = tid >> 7;
  float c = 0.f, fs = 0.f;
  for (int n = nh; n < N_; n += 2) {
    float f = fb[n * VD_ + d];
    c += sa[n] * f;
    fs += f;
  }
  pc[nh][tid & 127] = c;
  pf[nh][tid & 127] = fs;
  __syncthreads();
  if (tid < 128) {
    ctx[b * VD_ + q * 128 + tid] = pc[0][tid] + pc[1][tid];
    fmean[b * VD_ + q * 128 + tid] = (pf[0][tid] + pf[1][tid]) * (1.f / N_);
  }
}

// ---------------------------------------------------------------------------
// k_small: the three M=64 fp32 GEMMs in ONE launch (48 blocks of 64x64):
//   bx 0..7  : h0   = fmean @ W_init_h^T
//   bx 8..15 : c0   = fmean @ W_init_c^T
//   bx 16..47: gctx = ctx @ W_ih[:, :VD]^T + b_ih + b_hh
// ---------------------------------------------------------------------------
#define BK 16
__global__ __launch_bounds__(256) void k_small(
    const float* __restrict__ fmean, const float* __restrict__ ctx,
    const float* __restrict__ W_init_h, const float* __restrict__ W_init_c,
    const float* __restrict__ W_ih,
    const float* __restrict__ b_ih, const float* __restrict__ b_hh,
    float* __restrict__ hbuf, float* __restrict__ cbuf, float* __restrict__ gctx) {
  const float* A; const float* Bw; float* C;
  int ldb, ldc, n0;
  const float* bias1 = nullptr; const float* bias2 = nullptr;
  int bx = blockIdx.x;
  if (bx < 8)       { A = fmean; Bw = W_init_h; C = hbuf; ldb = VD_; ldc = HD_; n0 = bx * 64; }
  else if (bx < 16) { A = fmean; Bw = W_init_c; C = cbuf; ldb = VD_; ldc = HD_; n0 = (bx - 8) * 64; }
  else { A = ctx; Bw = W_ih; C = gctx; ldb = VD_ + ED_; ldc = G4_; n0 = (bx - 16) * 64;
         bias1 = b_ih; bias2 = b_hh; }

  __shared__ float As[BK][64];
  __shared__ float Bs[BK][64];
  int tid = threadIdx.x;
  int tm = tid & 15, tn = tid >> 4;
  int sr = tid >> 2, sk = (tid & 3) * 4;
  const float* arow = A + (size_t)sr * VD_;
  const float* brow = Bw + (size_t)(n0 + sr) * ldb;
  float acc[4][4] = {};

  for (int k0 = 0; k0 < VD_; k0 += BK) {
    float4 av = *(const float4*)(arow + k0 + sk);
    float4 bv = *(const float4*)(brow + k0 + sk);
    __syncthreads();
    As[sk + 0][sr] = av.x; As[sk + 1][sr] = av.y;
    As[sk + 2][sr] = av.z; As[sk + 3][sr] = av.w;
    Bs[sk + 0][sr] = bv.x; Bs[sk + 1][sr] = bv.y;
    Bs[sk + 2][sr] = bv.z; Bs[sk + 3][sr] = bv.w;
    __syncthreads();
#pragma unroll
    for (int kk = 0; kk < BK; ++kk) {
      float4 a4 = *(const float4*)&As[kk][tm * 4];
      float4 b4 = *(const float4*)&Bs[kk][tn * 4];
      acc[0][0] += a4.x * b4.x; acc[0][1] += a4.x * b4.y; acc[0][2] += a4.x * b4.z; acc[0][3] += a4.x * b4.w;
      acc[1][0] += a4.y * b4.x; acc[1][1] += a4.y * b4.y; acc[1][2] += a4.y * b4.z; acc[1][3] += a4.y * b4.w;
      acc[2][0] += a4.z * b4.x; acc[2][1] += a4.z * b4.y; acc[2][2] += a4.z * b4.z; acc[2][3] += a4.z * b4.w;
      acc[3][0] += a4.w * b4.x; acc[3][1] += a4.w * b4.y; acc[3][2] += a4.w * b4.z; acc[3][3] += a4.w * b4.w;
    }
  }
#pragma unroll
  for (int j = 0; j < 4; ++j) {
    int n = n0 + tn * 4 + j;
    float bb = (bias1 ? bias1[n] + bias2[n] : 0.f);
#pragma unroll
    for (int i = 0; i < 4; ++i) {
      int mm = tm * 4 + i;
      C[(size_t)mm * ldc + n] = acc[i][j] + bb;
    }
  }
}

// ---------------------------------------------------------------------------
// Staged bf16 MFMA GEMM: C[M,N] = A[M,K]@Bw[N,K]^T (+bias[n]) (+radd[m&63,n]).
// 128x128 block tile, BK=32, LDS-staged, 4 waves 2x2, wave 64x64 = 4x4 MFMAs
// of 16x16x32. M % 128 == 0; N edge clamped/guarded.
// ---------------------------------------------------------------------------
__global__ __launch_bounds__(256) void k_gemm_mfma(
    const unsigned short* __restrict__ A,
    const unsigned short* __restrict__ Bw,
    const float* __restrict__ bias,
    const float* __restrict__ radd, int ldr,
    float* __restrict__ C, int M, int Nn, int K) {
  __shared__ unsigned short As[128][32];
  __shared__ unsigned short Bs[128][32];
  int tid = threadIdx.x;
  int wave = tid >> 6, lane = tid & 63;
  int wm = wave & 1, wn = wave >> 1;
  int m0 = blockIdx.y * 128, n0 = blockIdx.x * 128;
  int l15 = lane & 15, quad = lane >> 4;
  int sr = tid >> 1, skq = (tid & 1) * 16;
  const unsigned short* ga = A + (size_t)(m0 + sr) * K + skq;
  int bn = n0 + sr; if (bn >= Nn) bn = Nn - 1;
  const unsigned short* gb = Bw + (size_t)bn * K + skq;

  f32x4 acc[4][4];
#pragma unroll
  for (int i = 0; i < 4; ++i)
#pragma unroll
    for (int j = 0; j < 4; ++j) acc[i][j] = (f32x4){0.f, 0.f, 0.f, 0.f};

  for (int k0 = 0; k0 < K; k0 += 32) {
    bf16x8 a0 = *(const bf16x8*)(ga + k0);
    bf16x8 a1 = *(const bf16x8*)(ga + k0 + 8);
    bf16x8 b0 = *(const bf16x8*)(gb + k0);
    bf16x8 b1 = *(const bf16x8*)(gb + k0 + 8);
    __syncthreads();
    *(bf16x8*)&As[sr][skq] = a0; *(bf16x8*)&As[sr][skq + 8] = a1;
    *(bf16x8*)&Bs[sr][skq] = b0; *(bf16x8*)&Bs[sr][skq + 8] = b1;
    __syncthreads();
    bf16x8 af[4], bfr[4];
#pragma unroll
    for (int mt = 0; mt < 4; ++mt)
      af[mt] = *(const bf16x8*)&As[wm * 64 + mt * 16 + l15][quad * 8];
#pragma unroll
    for (int nt = 0; nt < 4; ++nt)
      bfr[nt] = *(const bf16x8*)&Bs[wn * 64 + nt * 16 + l15][quad * 8];
#pragma unroll
    for (int mt = 0; mt < 4; ++mt)
#pragma unroll
      for (int nt = 0; nt < 4; ++nt)
        acc[mt][nt] = __builtin_amdgcn_mfma_f32_16x16x32_bf16(af[mt], bfr[nt], acc[mt][nt], 0, 0, 0);
  }

#pragma unroll
  for (int nt = 0; nt < 4; ++nt) {
    int n = n0 + wn * 64 + nt * 16 + l15;
    if (n < Nn) {
      float bb = bias ? bias[n] : 0.f;
#pragma unroll
      for (int mt = 0; mt < 4; ++mt) {
        int mbase = m0 + wm * 64 + mt * 16 + quad * 4;
#pragma unroll
        for (int r = 0; r < 4; ++r) {
          int mg = mbase + r;
          float ra = radd ? radd[(size_t)(mg & 63) * ldr + n] : 0.f;
          C[(size_t)mg * Nn + n] = acc[mt][nt][r] + bb + ra;
        }
      }
    }
  }
}

// ---------------------------------------------------------------------------
// Persistent fused LSTM: all 20 steps in one launch. Grid EXACTLY 256 blocks
// (= CU count, 1 block/CU -> co-resident) x 256 thr. Block bx owns hidx pair
// {2bx, 2bx+1}; wave w: hidx-lane = w&1, gate-pair = w>>1 (0:i,f  1:g,o).
// c kept in registers across steps (thread-private). h ping-pongs via global
// hall with a monotone-counter grid barrier + device fences per step.
// Also emits hall_bf (bf16) for the vocab GEMM.
// ---------------------------------------------------------------------------
__global__ __launch_bounds__(256) void k_lstm(
    const float* __restrict__ W_hh,    // [2048][512]
    const float* __restrict__ gpre,    // [T*64][2048]
    const float* __restrict__ h0,      // [64][512]
    const float* __restrict__ c0,      // [64][512]
    float* __restrict__ hall,          // [T][64][512]
    unsigned short* __restrict__ hall_bf,
    int* __restrict__ bar) {
  __shared__ float hs[64][68];   // [b][k-chunk], stride 68: 16B-aligned rows
  __shared__ float pg[64][2][2];
  int tid = threadIdx.x;
  int b = tid & 63, w = tid >> 6;
  int hl = w & 1, gpair = w >> 1;
  int hidx = blockIdx.x * 2 + hl;
  const float* wa = W_hh + (size_t)((gpair * 2 + 0) * HD_ + hidx) * HD_;
  const float* wb = W_hh + (size_t)((gpair * 2 + 1) * HD_ + hidx) * HD_;
  float c_reg = (gpair == 0) ? c0[(size_t)b * HD_ + hidx] : 0.f;

  for (int t = 0; t < T_; ++t) {
    const float* h_in = (t == 0) ? h0 : (hall + (size_t)(t - 1) * B_ * HD_);
    float acca = 0.f, accb = 0.f;
    for (int k0 = 0; k0 < HD_; k0 += 64) {
      __syncthreads();
      {
        int r = tid >> 2, ks = (tid & 3) * 16;
        const float* hp = h_in + r * HD_ + k0 + ks;
        float4 v0 = *(const float4*)(hp + 0);
        float4 v1 = *(const float4*)(hp + 4);
        float4 v2 = *(const float4*)(hp + 8);
        float4 v3 = *(const float4*)(hp + 12);
        *(float4*)&hs[r][ks + 0]  = v0;
        *(float4*)&hs[r][ks + 4]  = v1;
        *(float4*)&hs[r][ks + 8]  = v2;
        *(float4*)&hs[r][ks + 12] = v3;
      }
      __syncthreads();
#pragma unroll
      for (int kk = 0; kk < 64; kk += 4) {
        float4 hv = *(const float4*)&hs[b][kk];
        float4 a4 = *(const float4*)(wa + k0 + kk);
        float4 b4 = *(const float4*)(wb + k0 + kk);
        acca += hv.x * a4.x + hv.y * a4.y + hv.z * a4.z + hv.w * a4.w;
        accb += hv.x * b4.x + hv.y * b4.y + hv.z * b4.z + hv.w * b4.w;
      }
    }
    __syncthreads();
    if (gpair == 1) { pg[b][hl][0] = acca; pg[b][hl][1] = accb; }
    __syncthreads();
    if (gpair == 0) {
      const float* gp = gpre + (size_t)t * B_ * G4_ + (size_t)b * G4_;
      float gi = acca + gp[0 * HD_ + hidx];
      float gf = accb + gp[1 * HD_ + hidx];
      float gg = pg[b][hl][0] + gp[2 * HD_ + hidx];
      float go = pg[b][hl][1] + gp[3 * HD_ + hidx];
      c_reg = sigmoidf_(gf) * c_reg + sigmoidf_(gi) * tanhf(gg);
      float hv = sigmoidf_(go) * tanhf(c_reg);
      size_t oi = (size_t)t * B_ * HD_ + (size_t)b * HD_ + hidx;
      hall[oi] = hv;
      hall_bf[oi] = f2bf_(hv);
    }
    if (t < T_ - 1) {
      // grid barrier, epoch t+1: release stores, arrive, spin, acquire.
      __threadfence();
      __syncthreads();
      if (tid == 0) {
        atomicAdd(bar, 1);
        int target = (t + 1) * NBLK_LSTM;
        while (atomicAdd(bar, 0) < target) __builtin_amdgcn_s_sleep(2);
        __threadfence();
      }
      __syncthreads();
    }
  }
}

// ---------------------------------------------------------------------------
// Fused log_softmax + softmax per row of logits [1280][10000] (softmax in
// place; log_softmax to out1).
// ---------------------------------------------------------------------------
__global__ void k_softmax(float* __restrict__ logits, float* __restrict__ out1) {
  __shared__ float red[8];
  int row = blockIdx.x, tid = threadIdx.x;
  int lane = tid & 63, wid = tid >> 6;
  float* lr = logits + (size_t)row * V_;
  float* o1 = out1 + (size_t)row * V_;
  const int NV4 = V_ / 4;  // 2500

  float m = -1e30f;
  for (int i = tid; i < NV4; i += 256) {
    float4 v = ((const float4*)lr)[i];
    m = fmaxf(m, fmaxf(fmaxf(v.x, v.y), fmaxf(v.z, v.w)));
  }
#pragma unroll
  for (int off = 32; off > 0; off >>= 1) m = fmaxf(m, __shfl_down(m, off, 64));
  if (lane == 0) red[4 + wid] = m;
  __syncthreads();
  m = fmaxf(fmaxf(red[4], red[5]), fmaxf(red[6], red[7]));

  float s = 0.f;
  for (int i = tid; i < NV4; i += 256) {
    float4 v = ((const float4*)lr)[i];
    s += __expf(v.x - m) + __expf(v.y - m) + __expf(v.z - m) + __expf(v.w - m);
  }
#pragma unroll
  for (int off = 32; off > 0; off >>= 1) s += __shfl_down(s, off, 64);
  if (lane == 0) red[wid] = s;
  __syncthreads();
  s = red[0] + red[1] + red[2] + red[3];
  float ls = __logf(s), inv = 1.f / s;

  for (int i = tid; i < NV4; i += 256) {
    float4 v = ((const float4*)lr)[i];
    float4 a, bb;
    a.x = v.x - m - ls; a.y = v.y - m - ls; a.z = v.z - m - ls; a.w = v.w - m - ls;
    bb.x = __expf(v.x - m) * inv; bb.y = __expf(v.y - m) * inv;
    bb.z = __expf(v.z - m) * inv; bb.w = __expf(v.w - m) * inv;
    ((float4*)o1)[i] = a;
    ((float4*)lr)[i] = bb;
  }
}

// ---------------------------------------------------------------------------
extern "C" void kernel_launch(void* const* d_in, const int* in_sizes, int n_in,
                              void* d_out, int out_size, void* d_ws, size_t ws_size,
                              hipStream_t stream) {
  const float* features = (const float*)d_in[0];
  const int*   captions = (const int*)d_in[1];
  const float* W_init_h = (const float*)d_in[2];
  const float* W_init_c = (const float*)d_in[3];
  const float* W_av     = (const float*)d_in[4];
  // d_in[5] b_av, d_in[6] W_ah, d_in[7] b_ah: cancel inside softmax over n.
  const float* embed    = (const float*)d_in[8];
  const float* W_ih     = (const float*)d_in[9];
  const float* W_hh     = (const float*)d_in[10];
  const float* b_ih     = (const float*)d_in[11];
  const float* b_hh     = (const float*)d_in[12];
  const float* W_out    = (const float*)d_in[13];
  const float* b_out    = (const float*)d_in[14];

  float* ws    = (float*)d_ws;
  float* fmean = ws;                             // 32768
  float* ctx   = fmean + B_ * VD_;               // 32768
  float* hbuf  = ctx + B_ * VD_;                 // 32768
  float* cbuf  = hbuf + B_ * HD_;                // 32768
  float* gctx  = cbuf + B_ * HD_;                // 131072
  float* svg   = gctx + (size_t)B_ * G4_;        // 12544 -> pad 12608
  float* gpre  = svg + 12608;                    // 2621440
  float* hall  = gpre + (size_t)T_ * B_ * G4_;   // 655360
  int*   bar   = (int*)(hall + (size_t)T_ * B_ * HD_);   // 64 floats
  unsigned short* wout_bf = (unsigned short*)((float*)bar + 64);   // 5,120,000
  unsigned short* hall_bf = wout_bf + (size_t)V_ * HD_;            // 655,360
  unsigned short* wihe_bf = hall_bf + (size_t)T_ * B_ * HD_;       // 1,048,576
  unsigned short* emb_bf  = wihe_bf + (size_t)G4_ * ED_;           // 655,360
  // total ~29.2 MB

  float* out1   = (float*)d_out;                     // log_softmax [T,B,V]
  float* logits = out1 + (size_t)T_ * B_ * V_;       // softmax slot = scratch

  hipMemsetAsync(bar, 0, 64, stream);

  k_prep<<<6664, 256, 0, stream>>>(W_out, W_ih, embed, captions,
                                   wout_bf, wihe_bf, emb_bf);
  k_attn1<<<dim3(B_, 4), 256, 0, stream>>>(features, W_av, svg);
  k_attn2<<<dim3(B_, 4), 256, 0, stream>>>(features, svg, fmean, ctx);
  k_small<<<48, 256, 0, stream>>>(fmean, ctx, W_init_h, W_init_c, W_ih,
                                  b_ih, b_hh, hbuf, cbuf, gctx);

  // gpre[t*64+b, :] = emb_bf @ wihe_bf^T + gctx[b, :]  (gctx includes biases)
  k_gemm_mfma<<<dim3(G4_ / 128, (T_ * B_) / 128), 256, 0, stream>>>(
      emb_bf, wihe_bf, nullptr, gctx, G4_, gpre, T_ * B_, G4_, ED_);

  // all 20 LSTM steps, one persistent launch
  k_lstm<<<NBLK_LSTM, 256, 0, stream>>>(W_hh, gpre, hbuf, cbuf, hall, hall_bf, bar);

  // logits = hall @ W_out^T + b_out  (bf16 MFMA, fp32 accumulate)
  k_gemm_mfma<<<dim3((V_ + 127) / 128, (T_ * B_) / 128), 256, 0, stream>>>(
      hall_bf, wout_bf, b_out, nullptr, 0, logits, T_ * B_, V_, HD_);

  k_softmax<<<T_ * B_, 256, 0, stream>>>(logits, out1);
}

// Round 4
// 679.649 us; speedup vs baseline: 2.1955x; 2.1955x over previous
//
#include <hip/hip_runtime.h>
#include <math.h>

#define B_   64
#define N_   196
#define VD_  512
#define ED_  512
#define HD_  512
#define V_   10000
#define T_   20
#define G4_  2048   // 4*HD

typedef __attribute__((ext_vector_type(8))) short bf16x8;
typedef __attribute__((ext_vector_type(4))) float f32x4;

static __device__ __forceinline__ float sigmoidf_(float x) {
  return 1.f / (1.f + __expf(-x));
}

static __device__ __forceinline__ unsigned short f2bf_(float x) {
  unsigned u = __float_as_uint(x);
  unsigned r = (u + 0x7FFFu + ((u >> 16) & 1u)) >> 16;   // RNE
  return (unsigned short)r;
}

// ---------------------------------------------------------------------------
// k_prep: all fp32->bf16 casts + embedding gather-cast, one launch.
//   seg0 [0,5000):    W_out [10000][512]   -> wout_bf
//   seg1 [5000,6024): W_ih[:,512:1024]     -> wihe_bf [2048][512]
//   seg2 [6024,6664): embed[captions[b,t]] -> emb_bf  [t*64+b][512]
//   seg3 [6664,7688): W_hh  [2048][512]    -> whh_bf
// ---------------------------------------------------------------------------
__global__ void k_prep(const float* __restrict__ W_out,
                       const float* __restrict__ W_ih,
                       const float* __restrict__ W_hh,
                       const float* __restrict__ embed,
                       const int* __restrict__ caps,
                       unsigned short* __restrict__ wout_bf,
                       unsigned short* __restrict__ wihe_bf,
                       unsigned short* __restrict__ whh_bf,
                       unsigned short* __restrict__ emb_bf) {
  int bx = blockIdx.x, tid = threadIdx.x;
  float4 v; unsigned short* dst; int i;
  if (bx < 5000) {
    i = bx * 256 + tid;                       // float4 idx into W_out
    v = ((const float4*)W_out)[i];
    dst = wout_bf;
  } else if (bx < 6024) {
    i = (bx - 5000) * 256 + tid;              // 0..262143
    int j = i >> 7, kk = (i & 127) << 2;
    v = *(const float4*)(W_ih + (size_t)j * (VD_ + ED_) + VD_ + kk);
    dst = wihe_bf;
  } else if (bx < 6664) {
    i = (bx - 6024) * 256 + tid;              // 0..163839
    int row = i >> 7;                          // t*64+b
    int b = row & 63, t = row >> 6;
    v = *(const float4*)(embed + (size_t)caps[b * T_ + t] * ED_ + ((i & 127) << 2));
    dst = emb_bf;
  } else {
    i = (bx - 6664) * 256 + tid;              // 0..262143
    v = ((const float4*)W_hh)[i];
    dst = whh_bf;
  }
  ushort4 o;
  o.x = f2bf_(v.x); o.y = f2bf_(v.y); o.z = f2bf_(v.z); o.w = f2bf_(v.w);
  ((ushort4*)dst)[i] = o;
}

// ---------------------------------------------------------------------------
// k_attn1: attention logits svg[b][n] = feat[b,n,:] . W_av  (att_h/b cancel
// in softmax over n). grid (64 b, 4 n-chunks of 49); wave handles one n.
// ---------------------------------------------------------------------------
__global__ void k_attn1(const float* __restrict__ feat,
                        const float* __restrict__ W_av,
                        float* __restrict__ svg) {
  int b = blockIdx.x, q = blockIdx.y;
  int tid = threadIdx.x, lane = tid & 63, w = tid >> 6;
  const float* fb = feat + (size_t)b * (N_ * VD_);
  float4 wv0 = *(const float4*)(W_av + lane * 8);
  float4 wv1 = *(const float4*)(W_av + lane * 8 + 4);
  int nbase = q * 49;
  for (int n = nbase + w; n < nbase + 49; n += 4) {
    const float* fp = fb + n * VD_ + lane * 8;
    float4 f0 = *(const float4*)fp;
    float4 f1 = *(const float4*)(fp + 4);
    float p = f0.x * wv0.x + f0.y * wv0.y + f0.z * wv0.z + f0.w * wv0.w
            + f1.x * wv1.x + f1.y * wv1.y + f1.z * wv1.z + f1.w * wv1.w;
#pragma unroll
    for (int off = 32; off > 0; off >>= 1) p += __shfl_down(p, off, 64);
    if (lane == 0) svg[b * N_ + n] = p;
  }
}

// ---------------------------------------------------------------------------
// k_attn2: softmax(svg[b]) -> weights; ctx + fmean for a 128-dim chunk.
// grid (64 b, 4 d-chunks).
// ---------------------------------------------------------------------------
__global__ void k_attn2(const float* __restrict__ feat,
                        const float* __restrict__ svg,
                        float* __restrict__ fmean,
                        float* __restrict__ ctx) {
  __shared__ float sa[200];
  __shared__ float red[8];
  __shared__ float pc[2][128];
  __shared__ float pf[2][128];
  int b = blockIdx.x, q = blockIdx.y;
  int tid = threadIdx.x, lane = tid & 63, w = tid >> 6;
  const float* fb = feat + (size_t)b * (N_ * VD_);

  float v = (tid < N_) ? svg[b * N_ + tid] : -1e30f;
  float m = v;
#pragma unroll
  for (int off = 32; off > 0; off >>= 1) m = fmaxf(m, __shfl_down(m, off, 64));
  if (lane == 0) red[w] = m;
  __syncthreads();
  m = fmaxf(fmaxf(red[0], red[1]), fmaxf(red[2], red[3]));

  float e = (tid < N_) ? __expf(v - m) : 0.f;
  float s = e;
#pragma unroll
  for (int off = 32; off > 0; off >>= 1) s += __shfl_down(s, off, 64);
  if (lane == 0) red[4 + w] = s;
  __syncthreads();
  float inv = 1.f / (red[4] + red[5] + red[6] + red[7]);
  if (tid < N_) sa[tid] = e * inv;
  __syncthreads();

  int d = q * 128 + (tid & 127);
  int nh = tid >> 7;
  float c = 0.f, fs = 0.f;
  for (int n = nh; n < N_; n += 2) {
    float f = fb[n * VD_ + d];
    c += sa[n] * f;
    fs += f;
  }
  pc[nh][tid & 127] = c;
  pf[nh][tid & 127] = fs;
  __syncthreads();
  if (tid < 128) {
    ctx[b * VD_ + q * 128 + tid] = pc[0][tid] + pc[1][tid];
    fmean[b * VD_ + q * 128 + tid] = (pf[0][tid] + pf[1][tid]) * (1.f / N_);
  }
}

// ---------------------------------------------------------------------------
// k_small: three M=64 fp32 GEMMs in one launch (48 blocks):
//   bx 0..7  : h0   = fmean @ W_init_h^T   (+ bf16 copy for step 0)
//   bx 8..15 : c0   = fmean @ W_init_c^T
//   bx 16..47: gctx = ctx @ W_ih[:, :VD]^T + b_ih + b_hh
// ---------------------------------------------------------------------------
#define BK 16
__global__ __launch_bounds__(256) void k_small(
    const float* __restrict__ fmean, const float* __restrict__ ctx,
    const float* __restrict__ W_init_h, const float* __restrict__ W_init_c,
    const float* __restrict__ W_ih,
    const float* __restrict__ b_ih, const float* __restrict__ b_hh,
    float* __restrict__ hbuf, float* __restrict__ cbuf, float* __restrict__ gctx,
    unsigned short* __restrict__ h0_bf) {
  const float* A; const float* Bw; float* C;
  int ldb, ldc, n0;
  const float* bias1 = nullptr; const float* bias2 = nullptr;
  unsigned short* hb = nullptr;
  int bx = blockIdx.x;
  if (bx < 8)       { A = fmean; Bw = W_init_h; C = hbuf; ldb = VD_; ldc = HD_; n0 = bx * 64; hb = h0_bf; }
  else if (bx < 16) { A = fmean; Bw = W_init_c; C = cbuf; ldb = VD_; ldc = HD_; n0 = (bx - 8) * 64; }
  else { A = ctx; Bw = W_ih; C = gctx; ldb = VD_ + ED_; ldc = G4_; n0 = (bx - 16) * 64;
         bias1 = b_ih; bias2 = b_hh; }

  __shared__ float As[BK][64];
  __shared__ float Bs[BK][64];
  int tid = threadIdx.x;
  int tm = tid & 15, tn = tid >> 4;
  int sr = tid >> 2, sk = (tid & 3) * 4;
  const float* arow = A + (size_t)sr * VD_;
  const float* brow = Bw + (size_t)(n0 + sr) * ldb;
  float acc[4][4] = {};

  for (int k0 = 0; k0 < VD_; k0 += BK) {
    float4 av = *(const float4*)(arow + k0 + sk);
    float4 bv = *(const float4*)(brow + k0 + sk);
    __syncthreads();
    As[sk + 0][sr] = av.x; As[sk + 1][sr] = av.y;
    As[sk + 2][sr] = av.z; As[sk + 3][sr] = av.w;
    Bs[sk + 0][sr] = bv.x; Bs[sk + 1][sr] = bv.y;
    Bs[sk + 2][sr] = bv.z; Bs[sk + 3][sr] = bv.w;
    __syncthreads();
#pragma unroll
    for (int kk = 0; kk < BK; ++kk) {
      float4 a4 = *(const float4*)&As[kk][tm * 4];
      float4 b4 = *(const float4*)&Bs[kk][tn * 4];
      acc[0][0] += a4.x * b4.x; acc[0][1] += a4.x * b4.y; acc[0][2] += a4.x * b4.z; acc[0][3] += a4.x * b4.w;
      acc[1][0] += a4.y * b4.x; acc[1][1] += a4.y * b4.y; acc[1][2] += a4.y * b4.z; acc[1][3] += a4.y * b4.w;
      acc[2][0] += a4.z * b4.x; acc[2][1] += a4.z * b4.y; acc[2][2] += a4.z * b4.z; acc[2][3] += a4.z * b4.w;
      acc[3][0] += a4.w * b4.x; acc[3][1] += a4.w * b4.y; acc[3][2] += a4.w * b4.z; acc[3][3] += a4.w * b4.w;
    }
  }
#pragma unroll
  for (int j = 0; j < 4; ++j) {
    int n = n0 + tn * 4 + j;
    float bb = (bias1 ? bias1[n] + bias2[n] : 0.f);
#pragma unroll
    for (int i = 0; i < 4; ++i) {
      int mm = tm * 4 + i;
      float val = acc[i][j] + bb;
      C[(size_t)mm * ldc + n] = val;
      if (hb) hb[(size_t)mm * HD_ + n] = f2bf_(val);
    }
  }
}

// ---------------------------------------------------------------------------
// Staged bf16 MFMA GEMM: C[M,N] = A[M,K]@Bw[N,K]^T (+bias[n]) (+radd[m&63,n]).
// 128x128 block tile, BK=32, LDS-staged, 4 waves 2x2.
// ---------------------------------------------------------------------------
__global__ __launch_bounds__(256) void k_gemm_mfma(
    const unsigned short* __restrict__ A,
    const unsigned short* __restrict__ Bw,
    const float* __restrict__ bias,
    const float* __restrict__ radd, int ldr,
    float* __restrict__ C, int M, int Nn, int K) {
  __shared__ unsigned short As[128][32];
  __shared__ unsigned short Bs[128][32];
  int tid = threadIdx.x;
  int wave = tid >> 6, lane = tid & 63;
  int wm = wave & 1, wn = wave >> 1;
  int m0 = blockIdx.y * 128, n0 = blockIdx.x * 128;
  int l15 = lane & 15, quad = lane >> 4;
  int sr = tid >> 1, skq = (tid & 1) * 16;
  const unsigned short* ga = A + (size_t)(m0 + sr) * K + skq;
  int bn = n0 + sr; if (bn >= Nn) bn = Nn - 1;
  const unsigned short* gb = Bw + (size_t)bn * K + skq;

  f32x4 acc[4][4];
#pragma unroll
  for (int i = 0; i < 4; ++i)
#pragma unroll
    for (int j = 0; j < 4; ++j) acc[i][j] = (f32x4){0.f, 0.f, 0.f, 0.f};

  for (int k0 = 0; k0 < K; k0 += 32) {
    bf16x8 a0 = *(const bf16x8*)(ga + k0);
    bf16x8 a1 = *(const bf16x8*)(ga + k0 + 8);
    bf16x8 b0 = *(const bf16x8*)(gb + k0);
    bf16x8 b1 = *(const bf16x8*)(gb + k0 + 8);
    __syncthreads();
    *(bf16x8*)&As[sr][skq] = a0; *(bf16x8*)&As[sr][skq + 8] = a1;
    *(bf16x8*)&Bs[sr][skq] = b0; *(bf16x8*)&Bs[sr][skq + 8] = b1;
    __syncthreads();
    bf16x8 af[4], bfr[4];
#pragma unroll
    for (int mt = 0; mt < 4; ++mt)
      af[mt] = *(const bf16x8*)&As[wm * 64 + mt * 16 + l15][quad * 8];
#pragma unroll
    for (int nt = 0; nt < 4; ++nt)
      bfr[nt] = *(const bf16x8*)&Bs[wn * 64 + nt * 16 + l15][quad * 8];
#pragma unroll
    for (int mt = 0; mt < 4; ++mt)
#pragma unroll
      for (int nt = 0; nt < 4; ++nt)
        acc[mt][nt] = __builtin_amdgcn_mfma_f32_16x16x32_bf16(af[mt], bfr[nt], acc[mt][nt], 0, 0, 0);
  }

#pragma unroll
  for (int nt = 0; nt < 4; ++nt) {
    int n = n0 + wn * 64 + nt * 16 + l15;
    if (n < Nn) {
      float bb = bias ? bias[n] : 0.f;
#pragma unroll
      for (int mt = 0; mt < 4; ++mt) {
        int mbase = m0 + wm * 64 + mt * 16 + quad * 4;
#pragma unroll
        for (int r = 0; r < 4; ++r) {
          int mg = mbase + r;
          float ra = radd ? radd[(size_t)(mg & 63) * ldr + n] : 0.f;
          C[(size_t)mg * Nn + n] = acc[mt][nt][r] + bb + ra;
        }
      }
    }
  }
}

// ---------------------------------------------------------------------------
// One LSTM step via MFMA, fused cell update. Grid 16 blocks x 256 thr.
// Block owns hidx slice [n0, n0+32); wave w = gate g in {i,f,g,o}.
// gates[64,32] per gate = h_bf[64,512] @ W_hh_bf[g*512+n0 .. +32, :]^T,
// frags straight from global (h is 64KB, L2/L1-hot; W rows block-unique).
// Gate recombine through 32KB LDS, then elementwise update; h_out is bf16
// (next step's A operand AND the vocab GEMM's A rows).
// ---------------------------------------------------------------------------
__global__ __launch_bounds__(256) void k_step_mfma(
    const unsigned short* __restrict__ whh_bf,   // [2048][512] bf16
    const float* __restrict__ gpre_t,            // [64][2048]
    const unsigned short* __restrict__ h_in,     // [64][512] bf16
    float* __restrict__ c,                       // [64][512] fp32, in/out
    unsigned short* __restrict__ h_out) {        // [64][512] bf16
  __shared__ float gs[4][64][32];
  int tid = threadIdx.x;
  int g = tid >> 6, lane = tid & 63;
  int l15 = lane & 15, quad = lane >> 4;
  int n0 = blockIdx.x * 32;

  const unsigned short* ar = h_in + (size_t)l15 * HD_ + quad * 8;
  const unsigned short* br0 = whh_bf + (size_t)(g * HD_ + n0 + l15) * HD_ + quad * 8;
  const unsigned short* br1 = br0 + (size_t)16 * HD_;

  f32x4 acc[4][2];
#pragma unroll
  for (int i = 0; i < 4; ++i) { acc[i][0] = (f32x4){0,0,0,0}; acc[i][1] = (f32x4){0,0,0,0}; }

  for (int k0 = 0; k0 < HD_; k0 += 32) {
    bf16x8 b0 = *(const bf16x8*)(br0 + k0);
    bf16x8 b1 = *(const bf16x8*)(br1 + k0);
    bf16x8 a0 = *(const bf16x8*)(ar + k0);
    bf16x8 a1 = *(const bf16x8*)(ar + 16 * HD_ + k0);
    bf16x8 a2 = *(const bf16x8*)(ar + 32 * HD_ + k0);
    bf16x8 a3 = *(const bf16x8*)(ar + 48 * HD_ + k0);
    acc[0][0] = __builtin_amdgcn_mfma_f32_16x16x32_bf16(a0, b0, acc[0][0], 0, 0, 0);
    acc[1][0] = __builtin_amdgcn_mfma_f32_16x16x32_bf16(a1, b0, acc[1][0], 0, 0, 0);
    acc[2][0] = __builtin_amdgcn_mfma_f32_16x16x32_bf16(a2, b0, acc[2][0], 0, 0, 0);
    acc[3][0] = __builtin_amdgcn_mfma_f32_16x16x32_bf16(a3, b0, acc[3][0], 0, 0, 0);
    acc[0][1] = __builtin_amdgcn_mfma_f32_16x16x32_bf16(a0, b1, acc[0][1], 0, 0, 0);
    acc[1][1] = __builtin_amdgcn_mfma_f32_16x16x32_bf16(a1, b1, acc[1][1], 0, 0, 0);
    acc[2][1] = __builtin_amdgcn_mfma_f32_16x16x32_bf16(a2, b1, acc[2][1], 0, 0, 0);
    acc[3][1] = __builtin_amdgcn_mfma_f32_16x16x32_bf16(a3, b1, acc[3][1], 0, 0, 0);
  }

  // D layout: col = lane&15 (n), row = quad*4 + reg (m)
#pragma unroll
  for (int mt = 0; mt < 4; ++mt)
#pragma unroll
    for (int nt = 0; nt < 2; ++nt)
#pragma unroll
      for (int r = 0; r < 4; ++r)
        gs[g][mt * 16 + quad * 4 + r][nt * 16 + l15] = acc[mt][nt][r];
  __syncthreads();

#pragma unroll
  for (int j = 0; j < 8; ++j) {
    int p = tid + 256 * j;          // 0..2047
    int b = p >> 5, hl = p & 31;
    int hidx = n0 + hl;
    const float* gp = gpre_t + (size_t)b * G4_;
    float gi = gs[0][b][hl] + gp[hidx];
    float gf = gs[1][b][hl] + gp[HD_ + hidx];
    float gg = gs[2][b][hl] + gp[2 * HD_ + hidx];
    float go = gs[3][b][hl] + gp[3 * HD_ + hidx];
    size_t ci = (size_t)b * HD_ + hidx;
    float cn = sigmoidf_(gf) * c[ci] + sigmoidf_(gi) * tanhf(gg);
    c[ci] = cn;
    h_out[ci] = f2bf_(sigmoidf_(go) * tanhf(cn));
  }
}

// ---------------------------------------------------------------------------
// Fused log_softmax + softmax per row of logits [1280][10000] (softmax in
// place; log_softmax to out1).
// ---------------------------------------------------------------------------
__global__ void k_softmax(float* __restrict__ logits, float* __restrict__ out1) {
  __shared__ float red[8];
  int row = blockIdx.x, tid = threadIdx.x;
  int lane = tid & 63, wid = tid >> 6;
  float* lr = logits + (size_t)row * V_;
  float* o1 = out1 + (size_t)row * V_;
  const int NV4 = V_ / 4;  // 2500

  float m = -1e30f;
  for (int i = tid; i < NV4; i += 256) {
    float4 v = ((const float4*)lr)[i];
    m = fmaxf(m, fmaxf(fmaxf(v.x, v.y), fmaxf(v.z, v.w)));
  }
#pragma unroll
  for (int off = 32; off > 0; off >>= 1) m = fmaxf(m, __shfl_down(m, off, 64));
  if (lane == 0) red[4 + wid] = m;
  __syncthreads();
  m = fmaxf(fmaxf(red[4], red[5]), fmaxf(red[6], red[7]));

  float s = 0.f;
  for (int i = tid; i < NV4; i += 256) {
    float4 v = ((const float4*)lr)[i];
    s += __expf(v.x - m) + __expf(v.y - m) + __expf(v.z - m) + __expf(v.w - m);
  }
#pragma unroll
  for (int off = 32; off > 0; off >>= 1) s += __shfl_down(s, off, 64);
  if (lane == 0) red[wid] = s;
  __syncthreads();
  s = red[0] + red[1] + red[2] + red[3];
  float ls = __logf(s), inv = 1.f / s;

  for (int i = tid; i < NV4; i += 256) {
    float4 v = ((const float4*)lr)[i];
    float4 a, bb;
    a.x = v.x - m - ls; a.y = v.y - m - ls; a.z = v.z - m - ls; a.w = v.w - m - ls;
    bb.x = __expf(v.x - m) * inv; bb.y = __expf(v.y - m) * inv;
    bb.z = __expf(v.z - m) * inv; bb.w = __expf(v.w - m) * inv;
    ((float4*)o1)[i] = a;
    ((float4*)lr)[i] = bb;
  }
}

// ---------------------------------------------------------------------------
extern "C" void kernel_launch(void* const* d_in, const int* in_sizes, int n_in,
                              void* d_out, int out_size, void* d_ws, size_t ws_size,
                              hipStream_t stream) {
  const float* features = (const float*)d_in[0];
  const int*   captions = (const int*)d_in[1];
  const float* W_init_h = (const float*)d_in[2];
  const float* W_init_c = (const float*)d_in[3];
  const float* W_av     = (const float*)d_in[4];
  // d_in[5] b_av, d_in[6] W_ah, d_in[7] b_ah: cancel inside softmax over n.
  const float* embed    = (const float*)d_in[8];
  const float* W_ih     = (const float*)d_in[9];
  const float* W_hh     = (const float*)d_in[10];
  const float* b_ih     = (const float*)d_in[11];
  const float* b_hh     = (const float*)d_in[12];
  const float* W_out    = (const float*)d_in[13];
  const float* b_out    = (const float*)d_in[14];

  float* ws    = (float*)d_ws;
  float* fmean = ws;                             // 32768
  float* ctx   = fmean + B_ * VD_;               // 32768
  float* hbuf  = ctx + B_ * VD_;                 // 32768 (fp32 h0, debug/unused after)
  float* cbuf  = hbuf + B_ * HD_;                // 32768 (c, in-place across steps)
  float* gctx  = cbuf + B_ * HD_;                // 131072
  float* svg   = gctx + (size_t)B_ * G4_;        // 12544 -> pad 12608
  float* gpre  = svg + 12608;                    // 2,621,440
  unsigned short* wout_bf = (unsigned short*)(gpre + (size_t)T_ * B_ * G4_); // 5,120,000
  unsigned short* wihe_bf = wout_bf + (size_t)V_ * HD_;                      // 1,048,576
  unsigned short* whh_bf  = wihe_bf + (size_t)G4_ * ED_;                     // 1,048,576
  unsigned short* emb_bf  = whh_bf + (size_t)G4_ * HD_;                      // 655,360
  unsigned short* h0_bf   = emb_bf + (size_t)T_ * B_ * ED_;                  // 32,768
  unsigned short* hall_bf = h0_bf + (size_t)B_ * HD_;                        // 655,360
  // total ~28.8 MB

  float* out1   = (float*)d_out;                     // log_softmax [T,B,V]
  float* logits = out1 + (size_t)T_ * B_ * V_;       // softmax slot = scratch

  k_prep<<<7688, 256, 0, stream>>>(W_out, W_ih, W_hh, embed, captions,
                                   wout_bf, wihe_bf, whh_bf, emb_bf);
  k_attn1<<<dim3(B_, 4), 256, 0, stream>>>(features, W_av, svg);
  k_attn2<<<dim3(B_, 4), 256, 0, stream>>>(features, svg, fmean, ctx);
  k_small<<<48, 256, 0, stream>>>(fmean, ctx, W_init_h, W_init_c, W_ih,
                                  b_ih, b_hh, hbuf, cbuf, gctx, h0_bf);

  // gpre[t*64+b, :] = emb_bf @ wihe_bf^T + gctx[b, :]  (gctx includes biases)
  k_gemm_mfma<<<dim3(G4_ / 128, (T_ * B_) / 128), 256, 0, stream>>>(
      emb_bf, wihe_bf, nullptr, gctx, G4_, gpre, T_ * B_, G4_, ED_);

  // sequential LSTM: 20 cheap MFMA step launches; h ping-pongs through hall_bf
  for (int t = 0; t < T_; ++t) {
    const unsigned short* h_in = (t == 0) ? h0_bf : (hall_bf + (size_t)(t - 1) * B_ * HD_);
    k_step_mfma<<<16, 256, 0, stream>>>(
        whh_bf, gpre + (size_t)t * B_ * G4_, h_in, cbuf,
        hall_bf + (size_t)t * B_ * HD_);
  }

  // logits = hall @ W_out^T + b_out  (bf16 MFMA, fp32 accumulate)
  k_gemm_mfma<<<dim3((V_ + 127) / 128, (T_ * B_) / 128), 256, 0, stream>>>(
      hall_bf, wout_bf, b_out, nullptr, 0, logits, T_ * B_, V_, HD_);

  k_softmax<<<T_ * B_, 256, 0, stream>>>(logits, out1);
}

// Round 5
// 619.700 us; speedup vs baseline: 2.4079x; 1.0967x over previous
//
#include <hip/hip_runtime.h>
#include <math.h>

#define B_   64
#define N_   196
#define VD_  512
#define ED_  512
#define HD_  512
#define V_   10000
#define T_   20
#define G4_  2048   // 4*HD
#define LSTM_NBLK 32

typedef __attribute__((ext_vector_type(8))) short bf16x8;
typedef __attribute__((ext_vector_type(4))) float f32x4;

static __device__ __forceinline__ float sigmoidf_(float x) {
  return 1.f / (1.f + __expf(-x));
}

static __device__ __forceinline__ unsigned short f2bf_(float x) {
  unsigned u = __float_as_uint(x);
  unsigned r = (u + 0x7FFFu + ((u >> 16) & 1u)) >> 16;   // RNE
  return (unsigned short)r;
}

// ---------------------------------------------------------------------------
// k_prep: all fp32->bf16 casts + embedding gather-cast + attention logits,
// one launch (independent segments by blockIdx):
//   seg0 [0,5000):    W_out [10000][512]   -> wout_bf
//   seg1 [5000,6024): W_ih[:,512:1024]     -> wihe_bf [2048][512]
//   seg2 [6024,6664): embed[captions[b,t]] -> emb_bf  [t*64+b][512]
//   seg3 [6664,7688): W_hh  [2048][512]    -> whh_bf
//   seg4 [7688,7944): svg[b][n] = feat[b,n,:] . W_av   (attn logits;
//                     att_h/b_av/b_ah cancel in softmax over n)
// ---------------------------------------------------------------------------
__global__ void k_prep(const float* __restrict__ W_out,
                       const float* __restrict__ W_ih,
                       const float* __restrict__ W_hh,
                       const float* __restrict__ embed,
                       const int* __restrict__ caps,
                       const float* __restrict__ feat,
                       const float* __restrict__ W_av,
                       unsigned short* __restrict__ wout_bf,
                       unsigned short* __restrict__ wihe_bf,
                       unsigned short* __restrict__ whh_bf,
                       unsigned short* __restrict__ emb_bf,
                       float* __restrict__ svg) {
  int bx = blockIdx.x, tid = threadIdx.x;
  if (bx >= 7688) {   // attn1 segment
    int r = bx - 7688;
    int b = r >> 2, q = r & 3;
    int lane = tid & 63, w = tid >> 6;
    const float* fb = feat + (size_t)b * (N_ * VD_);
    float4 wv0 = *(const float4*)(W_av + lane * 8);
    float4 wv1 = *(const float4*)(W_av + lane * 8 + 4);
    int nbase = q * 49;
    for (int n = nbase + w; n < nbase + 49; n += 4) {
      const float* fp = fb + n * VD_ + lane * 8;
      float4 f0 = *(const float4*)fp;
      float4 f1 = *(const float4*)(fp + 4);
      float p = f0.x * wv0.x + f0.y * wv0.y + f0.z * wv0.z + f0.w * wv0.w
              + f1.x * wv1.x + f1.y * wv1.y + f1.z * wv1.z + f1.w * wv1.w;
#pragma unroll
      for (int off = 32; off > 0; off >>= 1) p += __shfl_down(p, off, 64);
      if (lane == 0) svg[b * N_ + n] = p;
    }
    return;
  }
  float4 v; unsigned short* dst; int i;
  if (bx < 5000) {
    i = bx * 256 + tid;
    v = ((const float4*)W_out)[i];
    dst = wout_bf;
  } else if (bx < 6024) {
    i = (bx - 5000) * 256 + tid;
    int j = i >> 7, kk = (i & 127) << 2;
    v = *(const float4*)(W_ih + (size_t)j * (VD_ + ED_) + VD_ + kk);
    dst = wihe_bf;
  } else if (bx < 6664) {
    i = (bx - 6024) * 256 + tid;
    int row = i >> 7;                          // t*64+b
    int b = row & 63, t = row >> 6;
    v = *(const float4*)(embed + (size_t)caps[b * T_ + t] * ED_ + ((i & 127) << 2));
    dst = emb_bf;
  } else {
    i = (bx - 6664) * 256 + tid;
    v = ((const float4*)W_hh)[i];
    dst = whh_bf;
  }
  ushort4 o;
  o.x = f2bf_(v.x); o.y = f2bf_(v.y); o.z = f2bf_(v.z); o.w = f2bf_(v.w);
  ((ushort4*)dst)[i] = o;
}

// ---------------------------------------------------------------------------
// k_attn2: softmax(svg[b]) -> weights; ctx + fmean for a 128-dim chunk.
// grid (64 b, 4 d-chunks). Second features read is L2/L3-hot.
// ---------------------------------------------------------------------------
__global__ void k_attn2(const float* __restrict__ feat,
                        const float* __restrict__ svg,
                        float* __restrict__ fmean,
                        float* __restrict__ ctx) {
  __shared__ float sa[200];
  __shared__ float red[8];
  __shared__ float pc[2][128];
  __shared__ float pf[2][128];
  int b = blockIdx.x, q = blockIdx.y;
  int tid = threadIdx.x, lane = tid & 63, w = tid >> 6;
  const float* fb = feat + (size_t)b * (N_ * VD_);

  float v = (tid < N_) ? svg[b * N_ + tid] : -1e30f;
  float m = v;
#pragma unroll
  for (int off = 32; off > 0; off >>= 1) m = fmaxf(m, __shfl_down(m, off, 64));
  if (lane == 0) red[w] = m;
  __syncthreads();
  m = fmaxf(fmaxf(red[0], red[1]), fmaxf(red[2], red[3]));

  float e = (tid < N_) ? __expf(v - m) : 0.f;
  float s = e;
#pragma unroll
  for (int off = 32; off > 0; off >>= 1) s += __shfl_down(s, off, 64);
  if (lane == 0) red[4 + w] = s;
  __syncthreads();
  float inv = 1.f / (red[4] + red[5] + red[6] + red[7]);
  if (tid < N_) sa[tid] = e * inv;
  __syncthreads();

  int d = q * 128 + (tid & 127);
  int nh = tid >> 7;
  float c = 0.f, fs = 0.f;
  for (int n = nh; n < N_; n += 2) {
    float f = fb[n * VD_ + d];
    c += sa[n] * f;
    fs += f;
  }
  pc[nh][tid & 127] = c;
  pf[nh][tid & 127] = fs;
  __syncthreads();
  if (tid < 128) {
    ctx[b * VD_ + q * 128 + tid] = pc[0][tid] + pc[1][tid];
    fmean[b * VD_ + q * 128 + tid] = (pf[0][tid] + pf[1][tid]) * (1.f / N_);
  }
}

// ---------------------------------------------------------------------------
// k_small: three M=64 fp32 GEMMs in one launch (48 blocks):
//   bx 0..7  : h0   = fmean @ W_init_h^T   (+ bf16 copy for step 0)
//   bx 8..15 : c0   = fmean @ W_init_c^T
//   bx 16..47: gctx = ctx @ W_ih[:, :VD]^T + b_ih + b_hh
// ---------------------------------------------------------------------------
#define BK 16
__global__ __launch_bounds__(256) void k_small(
    const float* __restrict__ fmean, const float* __restrict__ ctx,
    const float* __restrict__ W_init_h, const float* __restrict__ W_init_c,
    const float* __restrict__ W_ih,
    const float* __restrict__ b_ih, const float* __restrict__ b_hh,
    float* __restrict__ hbuf, float* __restrict__ cbuf, float* __restrict__ gctx,
    unsigned short* __restrict__ h0_bf) {
  const float* A; const float* Bw; float* C;
  int ldb, ldc, n0;
  const float* bias1 = nullptr; const float* bias2 = nullptr;
  unsigned short* hb = nullptr;
  int bx = blockIdx.x;
  if (bx < 8)       { A = fmean; Bw = W_init_h; C = hbuf; ldb = VD_; ldc = HD_; n0 = bx * 64; hb = h0_bf; }
  else if (bx < 16) { A = fmean; Bw = W_init_c; C = cbuf; ldb = VD_; ldc = HD_; n0 = (bx - 8) * 64; }
  else { A = ctx; Bw = W_ih; C = gctx; ldb = VD_ + ED_; ldc = G4_; n0 = (bx - 16) * 64;
         bias1 = b_ih; bias2 = b_hh; }

  __shared__ float As[BK][64];
  __shared__ float Bs[BK][64];
  int tid = threadIdx.x;
  int tm = tid & 15, tn = tid >> 4;
  int sr = tid >> 2, sk = (tid & 3) * 4;
  const float* arow = A + (size_t)sr * VD_;
  const float* brow = Bw + (size_t)(n0 + sr) * ldb;
  float acc[4][4] = {};

  for (int k0 = 0; k0 < VD_; k0 += BK) {
    float4 av = *(const float4*)(arow + k0 + sk);
    float4 bv = *(const float4*)(brow + k0 + sk);
    __syncthreads();
    As[sk + 0][sr] = av.x; As[sk + 1][sr] = av.y;
    As[sk + 2][sr] = av.z; As[sk + 3][sr] = av.w;
    Bs[sk + 0][sr] = bv.x; Bs[sk + 1][sr] = bv.y;
    Bs[sk + 2][sr] = bv.z; Bs[sk + 3][sr] = bv.w;
    __syncthreads();
#pragma unroll
    for (int kk = 0; kk < BK; ++kk) {
      float4 a4 = *(const float4*)&As[kk][tm * 4];
      float4 b4 = *(const float4*)&Bs[kk][tn * 4];
      acc[0][0] += a4.x * b4.x; acc[0][1] += a4.x * b4.y; acc[0][2] += a4.x * b4.z; acc[0][3] += a4.x * b4.w;
      acc[1][0] += a4.y * b4.x; acc[1][1] += a4.y * b4.y; acc[1][2] += a4.y * b4.z; acc[1][3] += a4.y * b4.w;
      acc[2][0] += a4.z * b4.x; acc[2][1] += a4.z * b4.y; acc[2][2] += a4.z * b4.z; acc[2][3] += a4.z * b4.w;
      acc[3][0] += a4.w * b4.x; acc[3][1] += a4.w * b4.y; acc[3][2] += a4.w * b4.z; acc[3][3] += a4.w * b4.w;
    }
  }
#pragma unroll
  for (int j = 0; j < 4; ++j) {
    int n = n0 + tn * 4 + j;
    float bb = (bias1 ? bias1[n] + bias2[n] : 0.f);
#pragma unroll
    for (int i = 0; i < 4; ++i) {
      int mm = tm * 4 + i;
      float val = acc[i][j] + bb;
      C[(size_t)mm * ldc + n] = val;
      if (hb) hb[(size_t)mm * HD_ + n] = f2bf_(val);
    }
  }
}

// ---------------------------------------------------------------------------
// Staged bf16 MFMA GEMM: C[M,N] = A[M,K]@Bw[N,K]^T (+bias[n]) (+radd[m&63,n]).
// 128x128 block tile, BK=32, LDS-staged, 4 waves 2x2.
// ---------------------------------------------------------------------------
__global__ __launch_bounds__(256) void k_gemm_mfma(
    const unsigned short* __restrict__ A,
    const unsigned short* __restrict__ Bw,
    const float* __restrict__ bias,
    const float* __restrict__ radd, int ldr,
    float* __restrict__ C, int M, int Nn, int K) {
  __shared__ unsigned short As[128][32];
  __shared__ unsigned short Bs[128][32];
  int tid = threadIdx.x;
  int wave = tid >> 6, lane = tid & 63;
  int wm = wave & 1, wn = wave >> 1;
  int m0 = blockIdx.y * 128, n0 = blockIdx.x * 128;
  int l15 = lane & 15, quad = lane >> 4;
  int sr = tid >> 1, skq = (tid & 1) * 16;
  const unsigned short* ga = A + (size_t)(m0 + sr) * K + skq;
  int bn = n0 + sr; if (bn >= Nn) bn = Nn - 1;
  const unsigned short* gb = Bw + (size_t)bn * K + skq;

  f32x4 acc[4][4];
#pragma unroll
  for (int i = 0; i < 4; ++i)
#pragma unroll
    for (int j = 0; j < 4; ++j) acc[i][j] = (f32x4){0.f, 0.f, 0.f, 0.f};

  for (int k0 = 0; k0 < K; k0 += 32) {
    bf16x8 a0 = *(const bf16x8*)(ga + k0);
    bf16x8 a1 = *(const bf16x8*)(ga + k0 + 8);
    bf16x8 b0 = *(const bf16x8*)(gb + k0);
    bf16x8 b1 = *(const bf16x8*)(gb + k0 + 8);
    __syncthreads();
    *(bf16x8*)&As[sr][skq] = a0; *(bf16x8*)&As[sr][skq + 8] = a1;
    *(bf16x8*)&Bs[sr][skq] = b0; *(bf16x8*)&Bs[sr][skq + 8] = b1;
    __syncthreads();
    bf16x8 af[4], bfr[4];
#pragma unroll
    for (int mt = 0; mt < 4; ++mt)
      af[mt] = *(const bf16x8*)&As[wm * 64 + mt * 16 + l15][quad * 8];
#pragma unroll
    for (int nt = 0; nt < 4; ++nt)
      bfr[nt] = *(const bf16x8*)&Bs[wn * 64 + nt * 16 + l15][quad * 8];
#pragma unroll
    for (int mt = 0; mt < 4; ++mt)
#pragma unroll
      for (int nt = 0; nt < 4; ++nt)
        acc[mt][nt] = __builtin_amdgcn_mfma_f32_16x16x32_bf16(af[mt], bfr[nt], acc[mt][nt], 0, 0, 0);
  }

#pragma unroll
  for (int nt = 0; nt < 4; ++nt) {
    int n = n0 + wn * 64 + nt * 16 + l15;
    if (n < Nn) {
      float bb = bias ? bias[n] : 0.f;
#pragma unroll
      for (int mt = 0; mt < 4; ++mt) {
        int mbase = m0 + wm * 64 + mt * 16 + quad * 4;
#pragma unroll
        for (int r = 0; r < 4; ++r) {
          int mg = mbase + r;
          float ra = radd ? radd[(size_t)(mg & 63) * ldr + n] : 0.f;
          C[(size_t)mg * Nn + n] = acc[mt][nt][r] + bb + ra;
        }
      }
    }
  }
}

// ---------------------------------------------------------------------------
// Persistent MFMA LSTM: all 20 steps, ONE launch. Grid 32 blocks x 256 thr
// (trivially co-resident). Block owns hidx slice [bx*16, bx*16+16); wave =
// gate g. Per step: gates slice = h[64,512] @ W_hh[g*512+slice,:]^T via
// 64 MFMAs/wave, recombine through 16KB LDS, elementwise update.
// c lives in REGISTERS across all steps. h ping-pongs through hall_bf.
// Grid barrier: one atomicAdd arrival per block + RELAXED-LOAD polling
// (R3's 56us/barrier pathology was 256 blocks RMW-spinning; 32 pollers
// with read-only spin is the fix), release/acquire via __threadfence.
// ---------------------------------------------------------------------------
__global__ __launch_bounds__(256) void k_lstm_mfma(
    const unsigned short* __restrict__ whh_bf,   // [2048][512] bf16
    const float* __restrict__ gpre,              // [T*64][2048]
    const unsigned short* __restrict__ h0_bf,    // [64][512] bf16
    const float* __restrict__ c0,                // [64][512] fp32
    unsigned short* __restrict__ hall_bf,        // [T][64][512] bf16
    int* __restrict__ bar) {
  __shared__ float gs[4][64][16];
  int tid = threadIdx.x;
  int g = tid >> 6, lane = tid & 63;
  int l15 = lane & 15, quad = lane >> 4;
  int n0 = blockIdx.x * 16;

  // thread's cell slice: p = tid + 256*j -> b = p>>4, hl = p&15
  float c_reg[4];
#pragma unroll
  for (int j = 0; j < 4; ++j) {
    int p = tid + 256 * j;
    c_reg[j] = c0[(size_t)(p >> 4) * HD_ + n0 + (p & 15)];
  }

  const unsigned short* br = whh_bf + (size_t)(g * HD_ + n0 + l15) * HD_ + quad * 8;

  for (int t = 0; t < T_; ++t) {
    const unsigned short* h_in =
        (t == 0) ? h0_bf : (hall_bf + (size_t)(t - 1) * B_ * HD_);
    const unsigned short* ar = h_in + (size_t)l15 * HD_ + quad * 8;

    f32x4 acc[4];
#pragma unroll
    for (int i = 0; i < 4; ++i) acc[i] = (f32x4){0.f, 0.f, 0.f, 0.f};

    for (int k0 = 0; k0 < HD_; k0 += 32) {
      bf16x8 b0 = *(const bf16x8*)(br + k0);
      bf16x8 a0 = *(const bf16x8*)(ar + k0);
      bf16x8 a1 = *(const bf16x8*)(ar + 16 * HD_ + k0);
      bf16x8 a2 = *(const bf16x8*)(ar + 32 * HD_ + k0);
      bf16x8 a3 = *(const bf16x8*)(ar + 48 * HD_ + k0);
      acc[0] = __builtin_amdgcn_mfma_f32_16x16x32_bf16(a0, b0, acc[0], 0, 0, 0);
      acc[1] = __builtin_amdgcn_mfma_f32_16x16x32_bf16(a1, b0, acc[1], 0, 0, 0);
      acc[2] = __builtin_amdgcn_mfma_f32_16x16x32_bf16(a2, b0, acc[2], 0, 0, 0);
      acc[3] = __builtin_amdgcn_mfma_f32_16x16x32_bf16(a3, b0, acc[3], 0, 0, 0);
    }

    // D layout: col = lane&15 (n within slice), row = quad*4 + reg (m=b)
#pragma unroll
    for (int mt = 0; mt < 4; ++mt)
#pragma unroll
      for (int r = 0; r < 4; ++r)
        gs[g][mt * 16 + quad * 4 + r][l15] = acc[mt][r];
    __syncthreads();

    const float* gpt = gpre + (size_t)t * B_ * G4_;
#pragma unroll
    for (int j = 0; j < 4; ++j) {
      int p = tid + 256 * j;
      int b = p >> 4, hl = p & 15;
      int hidx = n0 + hl;
      const float* gp = gpt + (size_t)b * G4_;
      float gi = gs[0][b][hl] + gp[hidx];
      float gf = gs[1][b][hl] + gp[HD_ + hidx];
      float gg = gs[2][b][hl] + gp[2 * HD_ + hidx];
      float go = gs[3][b][hl] + gp[3 * HD_ + hidx];
      float cn = sigmoidf_(gf) * c_reg[j] + sigmoidf_(gi) * tanhf(gg);
      c_reg[j] = cn;
      hall_bf[(size_t)t * B_ * HD_ + (size_t)b * HD_ + hidx] =
          f2bf_(sigmoidf_(go) * tanhf(cn));
    }

    if (t < T_ - 1) {
      __threadfence();     // release this block's hall writes (all threads)
      __syncthreads();     // all threads' fences done before arrival
      if (tid == 0) {
        atomicAdd(bar, 1);
        int target = (t + 1) * LSTM_NBLK;
        while (__hip_atomic_load(bar, __ATOMIC_RELAXED,
                                 __HIP_MEMORY_SCOPE_AGENT) < target)
          __builtin_amdgcn_s_sleep(2);
        __threadfence();   // acquire
      }
      __syncthreads();     // also protects gs reuse next step
    }
  }
}

// ---------------------------------------------------------------------------
// Fused log_softmax + softmax per row of logits [1280][10000] (softmax in
// place; log_softmax to out1).
// ---------------------------------------------------------------------------
__global__ void k_softmax(float* __restrict__ logits, float* __restrict__ out1) {
  __shared__ float red[8];
  int row = blockIdx.x, tid = threadIdx.x;
  int lane = tid & 63, wid = tid >> 6;
  float* lr = logits + (size_t)row * V_;
  float* o1 = out1 + (size_t)row * V_;
  const int NV4 = V_ / 4;  // 2500

  float m = -1e30f;
  for (int i = tid; i < NV4; i += 256) {
    float4 v = ((const float4*)lr)[i];
    m = fmaxf(m, fmaxf(fmaxf(v.x, v.y), fmaxf(v.z, v.w)));
  }
#pragma unroll
  for (int off = 32; off > 0; off >>= 1) m = fmaxf(m, __shfl_down(m, off, 64));
  if (lane == 0) red[4 + wid] = m;
  __syncthreads();
  m = fmaxf(fmaxf(red[4], red[5]), fmaxf(red[6], red[7]));

  float s = 0.f;
  for (int i = tid; i < NV4; i += 256) {
    float4 v = ((const float4*)lr)[i];
    s += __expf(v.x - m) + __expf(v.y - m) + __expf(v.z - m) + __expf(v.w - m);
  }
#pragma unroll
  for (int off = 32; off > 0; off >>= 1) s += __shfl_down(s, off, 64);
  if (lane == 0) red[wid] = s;
  __syncthreads();
  s = red[0] + red[1] + red[2] + red[3];
  float ls = __logf(s), inv = 1.f / s;

  for (int i = tid; i < NV4; i += 256) {
    float4 v = ((const float4*)lr)[i];
    float4 a, bb;
    a.x = v.x - m - ls; a.y = v.y - m - ls; a.z = v.z - m - ls; a.w = v.w - m - ls;
    bb.x = __expf(v.x - m) * inv; bb.y = __expf(v.y - m) * inv;
    bb.z = __expf(v.z - m) * inv; bb.w = __expf(v.w - m) * inv;
    ((float4*)o1)[i] = a;
    ((float4*)lr)[i] = bb;
  }
}

// ---------------------------------------------------------------------------
extern "C" void kernel_launch(void* const* d_in, const int* in_sizes, int n_in,
                              void* d_out, int out_size, void* d_ws, size_t ws_size,
                              hipStream_t stream) {
  const float* features = (const float*)d_in[0];
  const int*   captions = (const int*)d_in[1];
  const float* W_init_h = (const float*)d_in[2];
  const float* W_init_c = (const float*)d_in[3];
  const float* W_av     = (const float*)d_in[4];
  // d_in[5] b_av, d_in[6] W_ah, d_in[7] b_ah: cancel inside softmax over n.
  const float* embed    = (const float*)d_in[8];
  const float* W_ih     = (const float*)d_in[9];
  const float* W_hh     = (const float*)d_in[10];
  const float* b_ih     = (const float*)d_in[11];
  const float* b_hh     = (const float*)d_in[12];
  const float* W_out    = (const float*)d_in[13];
  const float* b_out    = (const float*)d_in[14];

  float* ws    = (float*)d_ws;
  float* fmean = ws;                             // 32768
  float* ctx   = fmean + B_ * VD_;               // 32768
  float* hbuf  = ctx + B_ * VD_;                 // 32768 (fp32 h0)
  float* cbuf  = hbuf + B_ * HD_;                // 32768 (c0)
  float* gctx  = cbuf + B_ * HD_;                // 131072
  float* svg   = gctx + (size_t)B_ * G4_;        // 12544 -> pad 12608
  float* gpre  = svg + 12608;                    // 2,621,440
  int*   bar   = (int*)(gpre + (size_t)T_ * B_ * G4_);                       // 64 ints
  unsigned short* wout_bf = (unsigned short*)(bar + 64);                     // 5,120,000
  unsigned short* wihe_bf = wout_bf + (size_t)V_ * HD_;                      // 1,048,576
  unsigned short* whh_bf  = wihe_bf + (size_t)G4_ * ED_;                     // 1,048,576
  unsigned short* emb_bf  = whh_bf + (size_t)G4_ * HD_;                      // 655,360
  unsigned short* h0_bf   = emb_bf + (size_t)T_ * B_ * ED_;                  // 32,768
  unsigned short* hall_bf = h0_bf + (size_t)B_ * HD_;                        // 655,360
  // total ~28.8 MB

  float* out1   = (float*)d_out;                     // log_softmax [T,B,V]
  float* logits = out1 + (size_t)T_ * B_ * V_;       // softmax slot = scratch

  hipMemsetAsync(bar, 0, 256, stream);

  k_prep<<<7944, 256, 0, stream>>>(W_out, W_ih, W_hh, embed, captions,
                                   features, W_av,
                                   wout_bf, wihe_bf, whh_bf, emb_bf, svg);
  k_attn2<<<dim3(B_, 4), 256, 0, stream>>>(features, svg, fmean, ctx);
  k_small<<<48, 256, 0, stream>>>(fmean, ctx, W_init_h, W_init_c, W_ih,
                                  b_ih, b_hh, hbuf, cbuf, gctx, h0_bf);

  // gpre[t*64+b, :] = emb_bf @ wihe_bf^T + gctx[b, :]  (gctx includes biases)
  k_gemm_mfma<<<dim3(G4_ / 128, (T_ * B_) / 128), 256, 0, stream>>>(
      emb_bf, wihe_bf, nullptr, gctx, G4_, gpre, T_ * B_, G4_, ED_);

  // all 20 LSTM steps, ONE launch (32-block persistent, load-spin barrier)
  k_lstm_mfma<<<LSTM_NBLK, 256, 0, stream>>>(
      whh_bf, gpre, h0_bf, cbuf, hall_bf, bar);

  // logits = hall @ W_out^T + b_out  (bf16 MFMA, fp32 accumulate)
  k_gemm_mfma<<<dim3((V_ + 127) / 128, (T_ * B_) / 128), 256, 0, stream>>>(
      hall_bf, wout_bf, b_out, nullptr, 0, logits, T_ * B_, V_, HD_);

  k_softmax<<<T_ * B_, 256, 0, stream>>>(logits, out1);
}